// Round 8
// baseline (414.471 us; speedup 1.0000x reference)
//
#include <hip/hip_runtime.h>
#include <hip/hip_bf16.h>
#include <math.h>

#define NN 100000
#define NE 1600000

#define NCB 391             // coarse buckets of 256 nodes
#define EB  2048            // edges per scatter block
#define SCT 512             // scatter block threads
#define EPT 4               // edges per thread = EB/SCT
#define HBK 128             // histogram blocks
#define NSB 782             // scatter blocks = ceil(NE/EB)
#define WPB 144             // wprep blocks (73728/512)
#define NGB 782             // gemm blocks = ceil(NN/128)

typedef __attribute__((ext_vector_type(8))) short short8;
typedef __attribute__((ext_vector_type(4))) float f32x4;
typedef __attribute__((ext_vector_type(2))) float f32x2;

// ---------- bf16 helpers ----------
__device__ __forceinline__ unsigned short f2bf(float f) {
  union { float f; unsigned int i; } v; v.f = f;
  unsigned int i = v.i;
  unsigned int r = (i + 0x7FFFu + ((i >> 16) & 1u)) >> 16;   // RNE
  return (unsigned short)r;
}
__device__ __forceinline__ float bflo(unsigned int u) {
  union { unsigned int i; float f; } v; v.i = u << 16; return v.f;
}
__device__ __forceinline__ float bfhi(unsigned int u) {
  union { unsigned int i; float f; } v; v.i = u & 0xFFFF0000u; return v.f;
}
// unpack bf16x2 -> packed f32x2 (compiler emits v_pk_add_f32 for f32x2 adds)
__device__ __forceinline__ f32x2 up2(unsigned int u) {
  union { unsigned int i; float f; } lo, hi;
  lo.i = u << 16; hi.i = u & 0xFFFF0000u;
  return (f32x2){lo.f, hi.f};
}

// ---------------- fused prep: bucket histogram (blocks 0..HBK-1) + weight
// prep (blocks HBK..HBK+WPB-1). wprep is CSR-independent; hide it here. ----
__global__ __launch_bounds__(512) void k_prep(
    const int* __restrict__ dst, int* __restrict__ part,
    const float* __restrict__ Wl0, const float* __restrict__ Wr0,
    const float* __restrict__ Wl1, const float* __restrict__ Wr1,
    const float* __restrict__ Wl2, const float* __restrict__ Wr2,
    unsigned short* __restrict__ B0, unsigned short* __restrict__ B1,
    unsigned short* __restrict__ B2) {
  if (blockIdx.x < HBK) {
    __shared__ int h[NCB];
    for (int i = threadIdx.x; i < NCB; i += 512) h[i] = 0;
    __syncthreads();
    int stride = HBK * 512;
    for (int e = blockIdx.x * 512 + threadIdx.x; e < NE; e += stride) {
      int d = dst[e];
      d = d < 0 ? 0 : (d >= NN ? NN - 1 : d);
      atomicAdd(&h[d >> 8], 1);
    }
    __syncthreads();
    for (int i = threadIdx.x; i < NCB; i += 512) part[blockIdx.x * NCB + i] = h[i];
  } else {
    int idx = (blockIdx.x - HBK) * 512 + threadIdx.x;   // [0, 73728)
    if (idx < 32768) {
      int n = idx >> 7, k = idx & 127;
      float v = (n < 128) ? Wl0[k * 128 + n] : Wr0[k * 128 + (n - 128)];
      B0[idx] = f2bf(v);
    } else if (idx < 65536) {
      int j = idx - 32768;
      int n = j >> 7, k = j & 127;
      float v = (n < 128) ? Wl1[k * 128 + n] : Wr1[k * 128 + (n - 128)];
      B1[j] = f2bf(v);
    } else if (idx < 73728) {
      int j = idx - 65536;
      int n = j >> 7, k = j & 127;
      float v = (n < 32) ? Wl2[k * 32 + n] : Wr2[k * 32 + (n - 32)];
      B2[j] = f2bf(v);
    }
  }
}

// ---------------- scan of coarse counts; zeroes ccur (64B-strided) --------
__global__ __launch_bounds__(512) void k_cscan(const int* __restrict__ part,
                                               int* __restrict__ cboff,
                                               int* __restrict__ ccur,
                                               int* __restrict__ csroff) {
  __shared__ int sd[512];
  int t = threadIdx.x;
  int v = 0;
  if (t < NCB) {
    int s0 = 0, s1 = 0, s2 = 0, s3 = 0;
    #pragma unroll 4
    for (int k = 0; k < HBK; k += 4) {
      s0 += part[(k + 0) * NCB + t];
      s1 += part[(k + 1) * NCB + t];
      s2 += part[(k + 2) * NCB + t];
      s3 += part[(k + 3) * NCB + t];
    }
    v = (s0 + s1) + (s2 + s3);
    ccur[t * 16] = 0;            // one counter per 64B line
  }
  sd[t] = v;
  __syncthreads();
  for (int st = 1; st < 512; st <<= 1) {
    int x = (t >= st) ? sd[t - st] : 0;
    __syncthreads();
    sd[t] += x;
    __syncthreads();
  }
  if (t < NCB) cboff[t] = sd[t] - v;
  if (t == NCB - 1) { cboff[NCB] = sd[t]; csroff[NN] = sd[t]; }
}

// ---------------- fused scatter + layer-0 MFMA GEMM ----------------
// 1564 = NSB+NGB blocks, 1:1 interleave: even bid -> scatter, odd -> gemm.
// Shorter scatter blocks (EB=2048) halve the serial pole and the drain tail.

__device__ __forceinline__ void cscatter_body(
    char* smem, int bid,
    const int* __restrict__ src, const int* __restrict__ dst,
    const int* __restrict__ cboff, int* __restrict__ ccur,
    unsigned int* __restrict__ ebuf) {
  int* lh = (int*)smem;                                  // NCB ints
  int t = threadIdx.x;
  int base = bid * EB;
  for (int i = t; i < NCB; i += SCT) lh[i] = 0;
  __syncthreads();
  unsigned int rk[EPT], pv[EPT];
  #pragma unroll
  for (int i = 0; i < EPT; i++) {
    int e = base + i * SCT + t;
    rk[i] = 0xFFFFFFFFu;
    pv[i] = 0;
    if (e < NE) {
      int d = dst[e];
      d = d < 0 ? 0 : (d >= NN ? NN - 1 : d);
      int s = src[e];
      s = s < 0 ? 0 : (s >= NN ? NN - 1 : s);
      int cb = d >> 8;
      int r = atomicAdd(&lh[cb], 1);
      rk[i] = (((unsigned int)cb) << 13) | (unsigned int)r;
      pv[i] = (((unsigned int)(d & 255)) << 17) | (unsigned int)s;
    }
  }
  __syncthreads();
  for (int i = t; i < NCB; i += SCT) {
    int c = lh[i];
    int g = c ? atomicAdd(&ccur[i * 16], c) : 0;
    lh[i] = cboff[i] + g;
  }
  __syncthreads();
  #pragma unroll
  for (int i = 0; i < EPT; i++) {
    unsigned int r = rk[i];
    if (r != 0xFFFFFFFFu) {
      ebuf[lh[r >> 13] + (r & 0x1FFF)] = pv[i];
    }
  }
}

// LDS-staged coalesced epilogue (NC=256): acc -> sA (bf16, MFMA layout) ->
// linear uint4 flush. Two passes: yl (cols 0..127, waves wn<2), then yr
// (cols 128..255, waves wn>=2, +bias). 128x128 bf16 @ stride 136 = 34 KB.
__device__ __forceinline__ void epilogue256(
    unsigned short* sA, int tid, int nb, int wn, int mbase, int nbase,
    int l15, int lq, f32x4 acc[4][4], const float* __restrict__ bias,
    unsigned short* __restrict__ yl, unsigned short* __restrict__ yr) {
  // pass 0: yl
  __syncthreads();
  if (wn < 2) {
    #pragma unroll
    for (int mi = 0; mi < 4; mi++)
      #pragma unroll
      for (int ni = 0; ni < 4; ni++) {
        int n = nbase + ni * 16 + l15;
        #pragma unroll
        for (int r = 0; r < 4; r++)
          sA[(mbase + mi * 16 + lq * 4 + r) * 136 + n] = f2bf(acc[mi][ni][r]);
      }
  }
  __syncthreads();
  {
    int row = tid >> 2, c0 = (tid & 3) * 32;
    int gn = nb + row;
    if (gn < NN) {
      #pragma unroll
      for (int k = 0; k < 4; k++) {
        uint4 v = *(uint4*)&sA[row * 136 + c0 + k * 8];
        *(uint4*)&yl[(size_t)gn * 128 + c0 + k * 8] = v;
      }
    }
  }
  // pass 1: yr (+bias)
  __syncthreads();
  if (wn >= 2) {
    #pragma unroll
    for (int mi = 0; mi < 4; mi++)
      #pragma unroll
      for (int ni = 0; ni < 4; ni++) {
        int n2 = nbase - 128 + ni * 16 + l15;
        float b = bias[n2];
        #pragma unroll
        for (int r = 0; r < 4; r++)
          sA[(mbase + mi * 16 + lq * 4 + r) * 136 + n2] =
              f2bf(acc[mi][ni][r] + b);
      }
  }
  __syncthreads();
  {
    int row = tid >> 2, c0 = (tid & 3) * 32;
    int gn = nb + row;
    if (gn < NN) {
      #pragma unroll
      for (int k = 0; k < 4; k++) {
        uint4 v = *(uint4*)&sA[row * 136 + c0 + k * 8];
        *(uint4*)&yr[(size_t)gn * 128 + c0 + k * 8] = v;
      }
    }
  }
}

__device__ __forceinline__ void mgemm0_body(
    char* smem, int bid, const float* __restrict__ A,
    const unsigned short* __restrict__ Bp, const float* __restrict__ bias,
    unsigned short* __restrict__ yl, unsigned short* __restrict__ yr) {
  unsigned short* sA = (unsigned short*)smem;   // 128*136*2 = 34.8 KB
  int tid = threadIdx.x;
  int nb  = bid * 128;

  #pragma unroll
  for (int i = 0; i < 8; i++) {
    int j = i * 512 + tid;
    int m = j >> 5;
    int k4 = (j & 31) * 4;
    int gn = nb + m;
    float4 v = make_float4(0.f, 0.f, 0.f, 0.f);
    if (gn < NN) v = *(const float4*)&A[gn * 128 + k4];
    unsigned int p0 = (unsigned int)f2bf(v.x) | ((unsigned int)f2bf(v.y) << 16);
    unsigned int p1 = (unsigned int)f2bf(v.z) | ((unsigned int)f2bf(v.w) << 16);
    *(uint2*)&sA[m * 136 + k4] = make_uint2(p0, p1);
  }
  __syncthreads();

  int wave = tid >> 6, lane = tid & 63;
  int l15 = lane & 15, lq = lane >> 4;
  int wm = wave & 1, wn = wave >> 1;
  int mbase = wm * 64;
  int nbase = wn * 64;

  f32x4 acc[4][4];
  #pragma unroll
  for (int mi = 0; mi < 4; mi++)
    #pragma unroll
    for (int ni = 0; ni < 4; ni++) acc[mi][ni] = (f32x4){0.f, 0.f, 0.f, 0.f};

  #pragma unroll
  for (int kc = 0; kc < 4; kc++) {
    int k0 = kc * 32 + lq * 8;
    short8 af[4], bfr[4];
    #pragma unroll
    for (int ni = 0; ni < 4; ni++)
      bfr[ni] = *(const short8*)&Bp[(nbase + ni * 16 + l15) * 128 + k0];
    #pragma unroll
    for (int mi = 0; mi < 4; mi++)
      af[mi] = *(const short8*)&sA[(mbase + mi * 16 + l15) * 136 + k0];
    #pragma unroll
    for (int mi = 0; mi < 4; mi++)
      #pragma unroll
      for (int ni = 0; ni < 4; ni++)
        acc[mi][ni] = __builtin_amdgcn_mfma_f32_16x16x32_bf16(
            af[mi], bfr[ni], acc[mi][ni], 0, 0, 0);
  }

  epilogue256(sA, tid, nb, wn, mbase, nbase, l15, lq, acc, bias, yl, yr);
}

__global__ __launch_bounds__(512, 4) void k_scatgemm(
    const int* __restrict__ src, const int* __restrict__ dst,
    const int* __restrict__ cboff, int* __restrict__ ccur,
    unsigned int* __restrict__ ebuf,
    const float* __restrict__ x, const unsigned short* __restrict__ B0,
    const float* __restrict__ bias,
    unsigned short* __restrict__ yl, unsigned short* __restrict__ yr) {
  __shared__ char smem[128 * 136 * 2];   // 34.8 KB union (gemm sA / scatter lh)
  int bid = blockIdx.x;
  if ((bid & 1) == 0) {
    cscatter_body(smem, bid >> 1, src, dst, cboff, ccur, ebuf);
  } else {
    mgemm0_body(smem, bid >> 1, x, B0, bias, yl, yr);
  }
}

// ---------------- per-coarse-bucket refine -> exact CSR (512 thr) ----------
__global__ __launch_bounds__(512) void k_crefine(
    const unsigned int* __restrict__ ebuf, const int* __restrict__ cboff,
    int* __restrict__ csroff, float* __restrict__ invd,
    int* __restrict__ csrsrc) {
  __shared__ int lh[256], pos[256], cur[256];
  int b = blockIdx.x, t = threadIdx.x;
  if (t < 256) { lh[t] = 0; cur[t] = 0; }
  __syncthreads();
  int beg = cboff[b], end = cboff[b + 1];
  for (int i = beg + t; i < end; i += 512) atomicAdd(&lh[ebuf[i] >> 17], 1);
  __syncthreads();
  int v = 0;
  if (t < 256) { v = lh[t]; pos[t] = v; }
  __syncthreads();
  for (int st = 1; st < 256; st <<= 1) {
    int x = (t < 256 && t >= st) ? pos[t - st] : 0;
    __syncthreads();
    if (t < 256) pos[t] += x;
    __syncthreads();
  }
  if (t < 256) {
    int nid = b * 256 + t;
    int mybase = cboff[b] + pos[t] - v;
    if (nid < NN) {
      csroff[nid] = mybase;
      invd[nid] = 1.0f / (float)(v < 1 ? 1 : v);
    }
    pos[t] = mybase;
  }
  __syncthreads();
  for (int i = beg + t; i < end; i += 512) {
    unsigned int u = ebuf[i];
    int local = u >> 17;
    int r = atomicAdd(&cur[local], 1);
    csrsrc[pos[local] + r] = (int)(u & 0x1FFFFu);
  }
}

// ---------------- standalone MFMA GEMM (layers 1,2; bf16 A) ----------------
template <int NC>
__global__ __launch_bounds__(512) void k_mgemm(
    const unsigned short* __restrict__ A, const unsigned short* __restrict__ Bp,
    const float* __restrict__ bias,
    unsigned short* __restrict__ yl, unsigned short* __restrict__ yr) {
  __shared__ unsigned short sA[128 * 136];
  int tid = threadIdx.x;
  int nb  = blockIdx.x * 128;

  #pragma unroll
  for (int i = 0; i < 4; i++) {
    int j = i * 512 + tid;
    int m = j >> 4;
    int k8 = (j & 15) * 8;
    int gn = nb + m;
    uint4 v = make_uint4(0, 0, 0, 0);
    if (gn < NN) v = *(const uint4*)&A[gn * 128 + k8];
    *(uint4*)&sA[m * 136 + k8] = v;
  }
  __syncthreads();

  int wave = tid >> 6, lane = tid & 63;
  int l15 = lane & 15, lq = lane >> 4;
  constexpr int MT = (NC == 256) ? 4 : 2;
  constexpr int NT = (NC == 256) ? 4 : 2;
  int wm, wn;
  if (NC == 256) { wm = wave & 1; wn = wave >> 1; }
  else           { wm = wave >> 1; wn = wave & 1; }
  int mbase = wm * (MT * 16);
  int nbase = wn * (NT * 16);

  f32x4 acc[MT][NT];
  #pragma unroll
  for (int mi = 0; mi < MT; mi++)
    #pragma unroll
    for (int ni = 0; ni < NT; ni++) acc[mi][ni] = (f32x4){0.f, 0.f, 0.f, 0.f};

  #pragma unroll
  for (int kc = 0; kc < 4; kc++) {
    int k0 = kc * 32 + lq * 8;
    short8 af[MT], bfr[NT];
    #pragma unroll
    for (int ni = 0; ni < NT; ni++)
      bfr[ni] = *(const short8*)&Bp[(nbase + ni * 16 + l15) * 128 + k0];
    #pragma unroll
    for (int mi = 0; mi < MT; mi++)
      af[mi] = *(const short8*)&sA[(mbase + mi * 16 + l15) * 136 + k0];
    #pragma unroll
    for (int mi = 0; mi < MT; mi++)
      #pragma unroll
      for (int ni = 0; ni < NT; ni++)
        acc[mi][ni] = __builtin_amdgcn_mfma_f32_16x16x32_bf16(
            af[mi], bfr[ni], acc[mi][ni], 0, 0, 0);
  }

  if (NC == 256) {
    f32x4 (*a)[4] = (f32x4(*)[4])acc;
    epilogue256(sA, tid, nb, wn, mbase, nbase, l15, lq, a, bias, yl, yr);
  } else {
    // single-pass staged epilogue: 128 rows x 64 cols bf16 @ stride 72 (18 KB)
    __syncthreads();
    #pragma unroll
    for (int mi = 0; mi < MT; mi++)
      #pragma unroll
      for (int ni = 0; ni < NT; ni++) {
        int n = nbase + ni * 16 + l15;            // 0..63
        float b = (n >= 32) ? bias[n - 32] : 0.f;
        #pragma unroll
        for (int r = 0; r < 4; r++)
          sA[(mbase + mi * 16 + lq * 4 + r) * 72 + n] =
              f2bf(acc[mi][ni][r] + b);
      }
    __syncthreads();
    int row = tid >> 2, c0 = (tid & 3) * 16;      // 16 cols (32 B) per thread
    int gn = nb + row;
    if (gn < NN) {
      uint4 v0 = *(uint4*)&sA[row * 72 + c0];
      uint4 v1 = *(uint4*)&sA[row * 72 + c0 + 8];
      if (c0 < 32) {
        *(uint4*)&yl[(size_t)gn * 32 + c0] = v0;
        *(uint4*)&yl[(size_t)gn * 32 + c0 + 8] = v1;
      } else {
        *(uint4*)&yr[(size_t)gn * 32 + (c0 - 32)] = v0;
        *(uint4*)&yr[(size_t)gn * 32 + (c0 - 32) + 8] = v1;
      }
    }
  }
}

// ---------------- pull aggregation, 128-dim (packed-f32 accumulate) --------
#define ACC8(u) do { \
  A01 += up2((u).x); A23 += up2((u).y); \
  A45 += up2((u).z); A67 += up2((u).w); } while (0)

__global__ __launch_bounds__(256) void k_agg128(
    const unsigned short* __restrict__ yl, const unsigned short* __restrict__ yr,
    const int* __restrict__ off, const int* __restrict__ csr,
    const float* __restrict__ invd, unsigned short* __restrict__ out, int relu) {
  int wid  = (blockIdx.x * 256 + threadIdx.x) >> 6;
  int lane = threadIdx.x & 63;
  if (wid >= NN) return;
  int beg = off[wid], end = off[wid + 1];
  int deg = end - beg;
  int q   = lane >> 4;    // edge slot within a 4-edge group
  int l16 = lane & 15;    // dim group: dims [l16*8, l16*8+8)
  const uint4* ylp = (const uint4*)yl;   // row = 16 uint4

  float sc = invd[wid];
  uint4 rv = ((const uint4*)yr)[wid * 16 + l16];

  f32x2 A01 = (f32x2){0.f, 0.f}, A23 = (f32x2){0.f, 0.f};
  f32x2 A45 = (f32x2){0.f, 0.f}, A67 = (f32x2){0.f, 0.f};

  for (int w0 = 0; w0 < deg; w0 += 64) {
    int ei = w0 + lane;
    int sv = (ei < deg) ? csr[beg + ei] : 0;
    int wcnt = deg - w0; if (wcnt > 64) wcnt = 64;
    int full = wcnt >> 2;
    int p = 0;
    for (; p + 4 <= full; p += 4) {          // 16 edges in flight
      int b = p * 4 + q;
      int s0 = __shfl(sv, b,      64);
      int s1 = __shfl(sv, b + 4,  64);
      int s2 = __shfl(sv, b + 8,  64);
      int s3 = __shfl(sv, b + 12, 64);
      uint4 u0 = ylp[s0 * 16 + l16];
      uint4 u1 = ylp[s1 * 16 + l16];
      uint4 u2 = ylp[s2 * 16 + l16];
      uint4 u3 = ylp[s3 * 16 + l16];
      ACC8(u0); ACC8(u1); ACC8(u2); ACC8(u3);
    }
    for (; p < full; p++) {
      int s0 = __shfl(sv, p * 4 + q, 64);
      uint4 u0 = ylp[s0 * 16 + l16];
      ACC8(u0);
    }
    int rem = wcnt & 3;
    if (rem && q < rem) {
      int s0 = __shfl(sv, full * 4 + q, 64);
      uint4 u0 = ylp[s0 * 16 + l16];
      ACC8(u0);
    }
  }

  float a0 = A01.x, a1 = A01.y, a2 = A23.x, a3 = A23.y;
  float a4 = A45.x, a5 = A45.y, a6 = A67.x, a7 = A67.y;

  // combine across the 4 quarter-groups
  a0 += __shfl_xor(a0, 16, 64); a0 += __shfl_xor(a0, 32, 64);
  a1 += __shfl_xor(a1, 16, 64); a1 += __shfl_xor(a1, 32, 64);
  a2 += __shfl_xor(a2, 16, 64); a2 += __shfl_xor(a2, 32, 64);
  a3 += __shfl_xor(a3, 16, 64); a3 += __shfl_xor(a3, 32, 64);
  a4 += __shfl_xor(a4, 16, 64); a4 += __shfl_xor(a4, 32, 64);
  a5 += __shfl_xor(a5, 16, 64); a5 += __shfl_xor(a5, 32, 64);
  a6 += __shfl_xor(a6, 16, 64); a6 += __shfl_xor(a6, 32, 64);
  a7 += __shfl_xor(a7, 16, 64); a7 += __shfl_xor(a7, 32, 64);

  float v0 = a0 * sc + bflo(rv.x), v1 = a1 * sc + bfhi(rv.x);
  float v2 = a2 * sc + bflo(rv.y), v3 = a3 * sc + bfhi(rv.y);
  float v4 = a4 * sc + bflo(rv.z), v5 = a5 * sc + bfhi(rv.z);
  float v6 = a6 * sc + bflo(rv.w), v7 = a7 * sc + bfhi(rv.w);
  if (relu) {
    v0 = fmaxf(v0, 0.f); v1 = fmaxf(v1, 0.f);
    v2 = fmaxf(v2, 0.f); v3 = fmaxf(v3, 0.f);
    v4 = fmaxf(v4, 0.f); v5 = fmaxf(v5, 0.f);
    v6 = fmaxf(v6, 0.f); v7 = fmaxf(v7, 0.f);
  }
  if (q == 0) {
    unsigned int p0 = (unsigned int)f2bf(v0) | ((unsigned int)f2bf(v1) << 16);
    unsigned int p1 = (unsigned int)f2bf(v2) | ((unsigned int)f2bf(v3) << 16);
    unsigned int p2 = (unsigned int)f2bf(v4) | ((unsigned int)f2bf(v5) << 16);
    unsigned int p3 = (unsigned int)f2bf(v6) | ((unsigned int)f2bf(v7) << 16);
    ((uint4*)out)[wid * 16 + l16] = make_uint4(p0, p1, p2, p3);
  }
}

// ---------------- 32-dim aggregation + log_softmax ----------------
#define ACC4(u) do { \
  A01 += up2((u).x); A23 += up2((u).y); } while (0)

__global__ __launch_bounds__(256) void k_agg32_lsm(
    const unsigned short* __restrict__ yl, const unsigned short* __restrict__ yr,
    const int* __restrict__ off, const int* __restrict__ csr,
    const float* __restrict__ invd, float* __restrict__ out) {
  int wid  = (blockIdx.x * 256 + threadIdx.x) >> 6;
  int lane = threadIdx.x & 63;
  if (wid >= NN) return;
  int beg = off[wid], end = off[wid + 1];
  int deg = end - beg;
  int q  = lane >> 3;     // edge slot 0..7
  int l8 = lane & 7;      // dims [l8*4, l8*4+4)
  const uint2* ylp = (const uint2*)yl;   // row = 8 uint2

  float sc = invd[wid];
  uint2 rv = ((const uint2*)yr)[wid * 8 + l8];

  f32x2 A01 = (f32x2){0.f, 0.f}, A23 = (f32x2){0.f, 0.f};

  for (int w0 = 0; w0 < deg; w0 += 64) {
    int ei = w0 + lane;
    int sv = (ei < deg) ? csr[beg + ei] : 0;
    int wcnt = deg - w0; if (wcnt > 64) wcnt = 64;
    int full = wcnt >> 3;
    int p = 0;
    for (; p + 2 <= full; p += 2) {         // 16 edges in flight
      int b = p * 8 + q;
      int s0 = __shfl(sv, b,     64);
      int s1 = __shfl(sv, b + 8, 64);
      uint2 u0 = ylp[s0 * 8 + l8];
      uint2 u1 = ylp[s1 * 8 + l8];
      ACC4(u0); ACC4(u1);
    }
    for (; p < full; p++) {
      int s0 = __shfl(sv, p * 8 + q, 64);
      uint2 u0 = ylp[s0 * 8 + l8];
      ACC4(u0);
    }
    int rem = wcnt & 7;
    if (rem && q < rem) {
      int s0 = __shfl(sv, full * 8 + q, 64);
      uint2 u0 = ylp[s0 * 8 + l8];
      ACC4(u0);
    }
  }

  float a0 = A01.x, a1 = A01.y, a2 = A23.x, a3 = A23.y;

  // combine across the 8 edge slots
  a0 += __shfl_xor(a0, 8, 64); a0 += __shfl_xor(a0, 16, 64); a0 += __shfl_xor(a0, 32, 64);
  a1 += __shfl_xor(a1, 8, 64); a1 += __shfl_xor(a1, 16, 64); a1 += __shfl_xor(a1, 32, 64);
  a2 += __shfl_xor(a2, 8, 64); a2 += __shfl_xor(a2, 16, 64); a2 += __shfl_xor(a2, 32, 64);
  a3 += __shfl_xor(a3, 8, 64); a3 += __shfl_xor(a3, 16, 64); a3 += __shfl_xor(a3, 32, 64);

  float v0 = a0 * sc + bflo(rv.x), v1 = a1 * sc + bfhi(rv.x);
  float v2 = a2 * sc + bflo(rv.y), v3 = a3 * sc + bfhi(rv.y);

  float m = fmaxf(fmaxf(v0, v1), fmaxf(v2, v3));
  m = fmaxf(m, __shfl_xor(m, 1, 64));
  m = fmaxf(m, __shfl_xor(m, 2, 64));
  m = fmaxf(m, __shfl_xor(m, 4, 64));
  float e0 = expf(v0 - m), e1 = expf(v1 - m);
  float e2 = expf(v2 - m), e3 = expf(v3 - m);
  float s = (e0 + e1) + (e2 + e3);
  s += __shfl_xor(s, 1, 64);
  s += __shfl_xor(s, 2, 64);
  s += __shfl_xor(s, 4, 64);
  float ls = logf(s);
  if (q == 0) {
    float4 o = make_float4(v0 - m - ls, v1 - m - ls, v2 - m - ls, v3 - m - ls);
    ((float4*)out)[wid * 8 + l8] = o;
  }
}

// ---------------- launch ----------------

extern "C" void kernel_launch(void* const* d_in, const int* in_sizes, int n_in,
                              void* d_out, int out_size, void* d_ws, size_t ws_size,
                              hipStream_t stream) {
  (void)in_sizes; (void)n_in; (void)out_size; (void)ws_size;
  const float* x   = (const float*)d_in[0];
  const int*   ei  = (const int*)d_in[1];
  const float* Wl0 = (const float*)d_in[2];
  const float* bl0 = (const float*)d_in[3];
  const float* Wr0 = (const float*)d_in[4];
  const float* Wl1 = (const float*)d_in[5];
  const float* bl1 = (const float*)d_in[6];
  const float* Wr1 = (const float*)d_in[7];
  const float* Wl2 = (const float*)d_in[8];
  const float* bl2 = (const float*)d_in[9];
  const float* Wr2 = (const float*)d_in[10];
  const int* srcI = ei;
  const int* dstI = ei + NE;

  char* w = (char*)d_ws;
  int*   cboff  = (int*)(w + (32 << 10));                       // 392 ints
  unsigned short* B0 = (unsigned short*)(w + (64 << 10));       // 64 KB
  unsigned short* B1 = (unsigned short*)(w + (160 << 10));      // 64 KB
  unsigned short* B2 = (unsigned short*)(w + (256 << 10));      // 16 KB
  int*   part   = (int*)(w + (288 << 10));                      // 128*391 = 200 KB
  int*   ccur   = (int*)(w + (496 << 10));                      // 391*64B = 25 KB
  int*   csroff = (int*)(w + (1024 << 10));                     // 400 KB
  float* invd   = (float*)(w + (1536 << 10));                   // 400 KB
  unsigned int* ebuf = (unsigned int*)(w + (size_t)(2) * 1024 * 1024);   // 6.4 MB
  int*   csrsrc = (int*)(w + (size_t)(9) * 1024 * 1024);                 // 6.4 MB
  unsigned short* ylb = (unsigned short*)(w + (size_t)(16) * 1024 * 1024); // 25.6 MB
  unsigned short* yrb = (unsigned short*)(w + (size_t)(48) * 1024 * 1024); // 25.6 MB
  unsigned short* hb  = (unsigned short*)(w + (size_t)(80) * 1024 * 1024); // 25.6 MB

  dim3 gg(NGB);   // 782

  // 1: histogram + weight prep (independent work, one dispatch)
  k_prep<<<HBK + WPB, 512, 0, stream>>>(dstI, part, Wl0, Wr0, Wl1, Wr1, Wl2, Wr2,
                                        B0, B1, B2);
  // 2: scan
  k_cscan<<<1, 512, 0, stream>>>(part, cboff, ccur, csroff);
  // 3: edge scatter + layer-0 GEMM (1:1 interleave, EB=2048)
  k_scatgemm<<<NSB + NGB, 512, 0, stream>>>(srcI, dstI, cboff, ccur, ebuf,
                                            x, B0, bl0, ylb, yrb);
  // 4: CSR refine
  k_crefine<<<NCB, 512, 0, stream>>>(ebuf, cboff, csroff, invd, csrsrc);
  // 5: layer-0 aggregation
  k_agg128<<<(NN * 64) / 256, 256, 0, stream>>>(ylb, yrb, csroff, csrsrc, invd, hb, 1);
  // 6: layer-1 GEMM
  k_mgemm<256><<<gg, 512, 0, stream>>>(hb, B1, bl1, ylb, yrb);
  // 7: layer-1 aggregation
  k_agg128<<<(NN * 64) / 256, 256, 0, stream>>>(ylb, yrb, csroff, csrsrc, invd, hb, 1);
  // 8: layer-2 GEMM (transform-first, 32-dim)
  k_mgemm<64><<<gg, 512, 0, stream>>>(hb, B2, bl2, ylb, yrb);
  // 9: layer-2 aggregation + log_softmax
  k_agg32_lsm<<<(NN * 64) / 256, 256, 0, stream>>>(ylb, yrb, csroff, csrsrc, invd,
                                                   (float*)d_out);
}

// Round 9
// 412.035 us; speedup vs baseline: 1.0059x; 1.0059x over previous
//
#include <hip/hip_runtime.h>
#include <hip/hip_bf16.h>
#include <math.h>

#define NN 100000
#define NE 1600000

#define NCB 391             // coarse buckets of 256 nodes
#define EB  4096            // edges per scatter block
#define SCT 512             // scatter block threads
#define EPT 8               // edges per thread = EB/SCT
#define HBK 128             // histogram blocks
#define NSB 391             // scatter blocks = ceil(NE/EB)
#define WPB 144             // wprep blocks (73728/512)
#define NGB 782             // gemm blocks = ceil(NN/128)
#define HGB 391             // half the gemm blocks
#define HNN 50048           // node split point = HGB*128

typedef __attribute__((ext_vector_type(8))) short short8;
typedef __attribute__((ext_vector_type(4))) float f32x4;
typedef __attribute__((ext_vector_type(2))) float f32x2;

// ---------- bf16 helpers ----------
__device__ __forceinline__ unsigned short f2bf(float f) {
  union { float f; unsigned int i; } v; v.f = f;
  unsigned int i = v.i;
  unsigned int r = (i + 0x7FFFu + ((i >> 16) & 1u)) >> 16;   // RNE
  return (unsigned short)r;
}
__device__ __forceinline__ float bflo(unsigned int u) {
  union { unsigned int i; float f; } v; v.i = u << 16; return v.f;
}
__device__ __forceinline__ float bfhi(unsigned int u) {
  union { unsigned int i; float f; } v; v.i = u & 0xFFFF0000u; return v.f;
}
__device__ __forceinline__ f32x2 up2(unsigned int u) {
  union { unsigned int i; float f; } lo, hi;
  lo.i = u << 16; hi.i = u & 0xFFFF0000u;
  return (f32x2){lo.f, hi.f};
}

// ---------------- fused prep ----------------
__global__ __launch_bounds__(512) void k_prep(
    const int* __restrict__ dst, int* __restrict__ part,
    const float* __restrict__ Wl0, const float* __restrict__ Wr0,
    const float* __restrict__ Wl1, const float* __restrict__ Wr1,
    const float* __restrict__ Wl2, const float* __restrict__ Wr2,
    unsigned short* __restrict__ B0, unsigned short* __restrict__ B1,
    unsigned short* __restrict__ B2) {
  if (blockIdx.x < HBK) {
    __shared__ int h[NCB];
    for (int i = threadIdx.x; i < NCB; i += 512) h[i] = 0;
    __syncthreads();
    int stride = HBK * 512;
    for (int e = blockIdx.x * 512 + threadIdx.x; e < NE; e += stride) {
      int d = dst[e];
      d = d < 0 ? 0 : (d >= NN ? NN - 1 : d);
      atomicAdd(&h[d >> 8], 1);
    }
    __syncthreads();
    for (int i = threadIdx.x; i < NCB; i += 512) part[blockIdx.x * NCB + i] = h[i];
  } else {
    int idx = (blockIdx.x - HBK) * 512 + threadIdx.x;   // [0, 73728)
    if (idx < 32768) {
      int n = idx >> 7, k = idx & 127;
      float v = (n < 128) ? Wl0[k * 128 + n] : Wr0[k * 128 + (n - 128)];
      B0[idx] = f2bf(v);
    } else if (idx < 65536) {
      int j = idx - 32768;
      int n = j >> 7, k = j & 127;
      float v = (n < 128) ? Wl1[k * 128 + n] : Wr1[k * 128 + (n - 128)];
      B1[j] = f2bf(v);
    } else if (idx < 73728) {
      int j = idx - 65536;
      int n = j >> 7, k = j & 127;
      float v = (n < 32) ? Wl2[k * 32 + n] : Wr2[k * 32 + (n - 32)];
      B2[j] = f2bf(v);
    }
  }
}

// ---------------- scan of coarse counts; zeroes ccur (64B-strided) --------
__global__ __launch_bounds__(512) void k_cscan(const int* __restrict__ part,
                                               int* __restrict__ cboff,
                                               int* __restrict__ ccur,
                                               int* __restrict__ csroff) {
  __shared__ int sd[512];
  int t = threadIdx.x;
  int v = 0;
  if (t < NCB) {
    int s0 = 0, s1 = 0, s2 = 0, s3 = 0;
    #pragma unroll 4
    for (int k = 0; k < HBK; k += 4) {
      s0 += part[(k + 0) * NCB + t];
      s1 += part[(k + 1) * NCB + t];
      s2 += part[(k + 2) * NCB + t];
      s3 += part[(k + 3) * NCB + t];
    }
    v = (s0 + s1) + (s2 + s3);
    ccur[t * 16] = 0;
  }
  sd[t] = v;
  __syncthreads();
  for (int st = 1; st < 512; st <<= 1) {
    int x = (t >= st) ? sd[t - st] : 0;
    __syncthreads();
    sd[t] += x;
    __syncthreads();
  }
  if (t < NCB) cboff[t] = sd[t] - v;
  if (t == NCB - 1) { cboff[NCB] = sd[t]; csroff[NN] = sd[t]; }
}

// ---------------- scatter body (proven R7) ----------------
__device__ __forceinline__ void cscatter_body(
    char* smem, int bid,
    const int* __restrict__ src, const int* __restrict__ dst,
    const int* __restrict__ cboff, int* __restrict__ ccur,
    unsigned int* __restrict__ ebuf) {
  int* lh = (int*)smem;                                  // NCB ints
  int t = threadIdx.x;
  int base = bid * EB;
  for (int i = t; i < NCB; i += SCT) lh[i] = 0;
  __syncthreads();
  unsigned int rk[EPT], pv[EPT];
  #pragma unroll
  for (int i = 0; i < EPT; i++) {
    int e = base + i * SCT + t;
    rk[i] = 0xFFFFFFFFu;
    pv[i] = 0;
    if (e < NE) {
      int d = dst[e];
      d = d < 0 ? 0 : (d >= NN ? NN - 1 : d);
      int s = src[e];
      s = s < 0 ? 0 : (s >= NN ? NN - 1 : s);
      int cb = d >> 8;
      int r = atomicAdd(&lh[cb], 1);
      rk[i] = (((unsigned int)cb) << 13) | (unsigned int)r;
      pv[i] = (((unsigned int)(d & 255)) << 17) | (unsigned int)s;
    }
  }
  __syncthreads();
  for (int i = t; i < NCB; i += SCT) {
    int c = lh[i];
    int g = c ? atomicAdd(&ccur[i * 16], c) : 0;
    lh[i] = cboff[i] + g;
  }
  __syncthreads();
  #pragma unroll
  for (int i = 0; i < EPT; i++) {
    unsigned int r = rk[i];
    if (r != 0xFFFFFFFFu) {
      ebuf[lh[r >> 13] + (r & 0x1FFF)] = pv[i];
    }
  }
}

// ---------------- LDS-staged coalesced epilogue (NC=256) ----------------
__device__ __forceinline__ void epilogue256(
    unsigned short* sA, int tid, int nb, int wn, int mbase, int nbase,
    int l15, int lq, f32x4 acc[4][4], const float* __restrict__ bias,
    unsigned short* __restrict__ yl, unsigned short* __restrict__ yr) {
  __syncthreads();
  if (wn < 2) {
    #pragma unroll
    for (int mi = 0; mi < 4; mi++)
      #pragma unroll
      for (int ni = 0; ni < 4; ni++) {
        int n = nbase + ni * 16 + l15;
        #pragma unroll
        for (int r = 0; r < 4; r++)
          sA[(mbase + mi * 16 + lq * 4 + r) * 136 + n] = f2bf(acc[mi][ni][r]);
      }
  }
  __syncthreads();
  {
    int row = tid >> 2, c0 = (tid & 3) * 32;
    int gn = nb + row;
    if (gn < NN) {
      #pragma unroll
      for (int k = 0; k < 4; k++) {
        uint4 v = *(uint4*)&sA[row * 136 + c0 + k * 8];
        *(uint4*)&yl[(size_t)gn * 128 + c0 + k * 8] = v;
      }
    }
  }
  __syncthreads();
  if (wn >= 2) {
    #pragma unroll
    for (int mi = 0; mi < 4; mi++)
      #pragma unroll
      for (int ni = 0; ni < 4; ni++) {
        int n2 = nbase - 128 + ni * 16 + l15;
        float b = bias[n2];
        #pragma unroll
        for (int r = 0; r < 4; r++)
          sA[(mbase + mi * 16 + lq * 4 + r) * 136 + n2] =
              f2bf(acc[mi][ni][r] + b);
      }
  }
  __syncthreads();
  {
    int row = tid >> 2, c0 = (tid & 3) * 32;
    int gn = nb + row;
    if (gn < NN) {
      #pragma unroll
      for (int k = 0; k < 4; k++) {
        uint4 v = *(uint4*)&sA[row * 136 + c0 + k * 8];
        *(uint4*)&yr[(size_t)gn * 128 + c0 + k * 8] = v;
      }
    }
  }
}

// ---------------- layer-0 GEMM body (fp32 A) ----------------
__device__ __forceinline__ void mgemm0_body(
    char* smem, int bid, const float* __restrict__ A,
    const unsigned short* __restrict__ Bp, const float* __restrict__ bias,
    unsigned short* __restrict__ yl, unsigned short* __restrict__ yr) {
  unsigned short* sA = (unsigned short*)smem;
  int tid = threadIdx.x;
  int nb  = bid * 128;

  #pragma unroll
  for (int i = 0; i < 8; i++) {
    int j = i * 512 + tid;
    int m = j >> 5;
    int k4 = (j & 31) * 4;
    int gn = nb + m;
    float4 v = make_float4(0.f, 0.f, 0.f, 0.f);
    if (gn < NN) v = *(const float4*)&A[gn * 128 + k4];
    unsigned int p0 = (unsigned int)f2bf(v.x) | ((unsigned int)f2bf(v.y) << 16);
    unsigned int p1 = (unsigned int)f2bf(v.z) | ((unsigned int)f2bf(v.w) << 16);
    *(uint2*)&sA[m * 136 + k4] = make_uint2(p0, p1);
  }
  __syncthreads();

  int wave = tid >> 6, lane = tid & 63;
  int l15 = lane & 15, lq = lane >> 4;
  int wm = wave & 1, wn = wave >> 1;
  int mbase = wm * 64;
  int nbase = wn * 64;

  f32x4 acc[4][4];
  #pragma unroll
  for (int mi = 0; mi < 4; mi++)
    #pragma unroll
    for (int ni = 0; ni < 4; ni++) acc[mi][ni] = (f32x4){0.f, 0.f, 0.f, 0.f};

  #pragma unroll
  for (int kc = 0; kc < 4; kc++) {
    int k0 = kc * 32 + lq * 8;
    short8 af[4], bfr[4];
    #pragma unroll
    for (int ni = 0; ni < 4; ni++)
      bfr[ni] = *(const short8*)&Bp[(nbase + ni * 16 + l15) * 128 + k0];
    #pragma unroll
    for (int mi = 0; mi < 4; mi++)
      af[mi] = *(const short8*)&sA[(mbase + mi * 16 + l15) * 136 + k0];
    #pragma unroll
    for (int mi = 0; mi < 4; mi++)
      #pragma unroll
      for (int ni = 0; ni < 4; ni++)
        acc[mi][ni] = __builtin_amdgcn_mfma_f32_16x16x32_bf16(
            af[mi], bfr[ni], acc[mi][ni], 0, 0, 0);
  }

  epilogue256((unsigned short*)smem, tid, nb, wn, mbase, nbase, l15, lq, acc,
              bias, yl, yr);
}

__global__ __launch_bounds__(512, 4) void k_scatgemm(
    const int* __restrict__ src, const int* __restrict__ dst,
    const int* __restrict__ cboff, int* __restrict__ ccur,
    unsigned int* __restrict__ ebuf,
    const float* __restrict__ x, const unsigned short* __restrict__ B0,
    const float* __restrict__ bias,
    unsigned short* __restrict__ yl, unsigned short* __restrict__ yr) {
  __shared__ char smem[128 * 136 * 2];   // 34.8 KB union
  int bid = blockIdx.x;
  int third = bid / 3;
  if (bid - third * 3 == 0) {
    cscatter_body(smem, third, src, dst, cboff, ccur, ebuf);
  } else {
    mgemm0_body(smem, bid - third - 1, x, B0, bias, yl, yr);
  }
}

// ---------------- per-coarse-bucket refine -> exact CSR (512 thr) ----------
__global__ __launch_bounds__(512) void k_crefine(
    const unsigned int* __restrict__ ebuf, const int* __restrict__ cboff,
    int* __restrict__ csroff, float* __restrict__ invd,
    int* __restrict__ csrsrc) {
  __shared__ int lh[256], pos[256], cur[256];
  int b = blockIdx.x, t = threadIdx.x;
  if (t < 256) { lh[t] = 0; cur[t] = 0; }
  __syncthreads();
  int beg = cboff[b], end = cboff[b + 1];
  for (int i = beg + t; i < end; i += 512) atomicAdd(&lh[ebuf[i] >> 17], 1);
  __syncthreads();
  int v = 0;
  if (t < 256) { v = lh[t]; pos[t] = v; }
  __syncthreads();
  for (int st = 1; st < 256; st <<= 1) {
    int x = (t < 256 && t >= st) ? pos[t - st] : 0;
    __syncthreads();
    if (t < 256) pos[t] += x;
    __syncthreads();
  }
  if (t < 256) {
    int nid = b * 256 + t;
    int mybase = cboff[b] + pos[t] - v;
    if (nid < NN) {
      csroff[nid] = mybase;
      invd[nid] = 1.0f / (float)(v < 1 ? 1 : v);
    }
    pos[t] = mybase;
  }
  __syncthreads();
  for (int i = beg + t; i < end; i += 512) {
    unsigned int u = ebuf[i];
    int local = u >> 17;
    int r = atomicAdd(&cur[local], 1);
    csrsrc[pos[local] + r] = (int)(u & 0x1FFFFu);
  }
}

// ---------------- bf16-A GEMM body (layers 1,2) ----------------
template <int NC>
__device__ __forceinline__ void mgemmN_body(
    unsigned short* sA, int nb, const unsigned short* __restrict__ A,
    const unsigned short* __restrict__ Bp, const float* __restrict__ bias,
    unsigned short* __restrict__ yl, unsigned short* __restrict__ yr) {
  int tid = threadIdx.x;
  #pragma unroll
  for (int i = 0; i < 4; i++) {
    int j = i * 512 + tid;
    int m = j >> 4;
    int k8 = (j & 15) * 8;
    int gn = nb + m;
    uint4 v = make_uint4(0, 0, 0, 0);
    if (gn < NN) v = *(const uint4*)&A[gn * 128 + k8];
    *(uint4*)&sA[m * 136 + k8] = v;
  }
  __syncthreads();

  int wave = tid >> 6, lane = tid & 63;
  int l15 = lane & 15, lq = lane >> 4;
  constexpr int MT = (NC == 256) ? 4 : 2;
  constexpr int NT = (NC == 256) ? 4 : 2;
  int wm, wn;
  if (NC == 256) { wm = wave & 1; wn = wave >> 1; }
  else           { wm = wave >> 1; wn = wave & 1; }
  int mbase = wm * (MT * 16);
  int nbase = wn * (NT * 16);

  f32x4 acc[MT][NT];
  #pragma unroll
  for (int mi = 0; mi < MT; mi++)
    #pragma unroll
    for (int ni = 0; ni < NT; ni++) acc[mi][ni] = (f32x4){0.f, 0.f, 0.f, 0.f};

  #pragma unroll
  for (int kc = 0; kc < 4; kc++) {
    int k0 = kc * 32 + lq * 8;
    short8 af[MT], bfr[NT];
    #pragma unroll
    for (int ni = 0; ni < NT; ni++)
      bfr[ni] = *(const short8*)&Bp[(nbase + ni * 16 + l15) * 128 + k0];
    #pragma unroll
    for (int mi = 0; mi < MT; mi++)
      af[mi] = *(const short8*)&sA[(mbase + mi * 16 + l15) * 136 + k0];
    #pragma unroll
    for (int mi = 0; mi < MT; mi++)
      #pragma unroll
      for (int ni = 0; ni < NT; ni++)
        acc[mi][ni] = __builtin_amdgcn_mfma_f32_16x16x32_bf16(
            af[mi], bfr[ni], acc[mi][ni], 0, 0, 0);
  }

  if (NC == 256) {
    f32x4 (*a)[4] = (f32x4(*)[4])acc;
    epilogue256(sA, tid, nb, wn, mbase, nbase, l15, lq, a, bias, yl, yr);
  } else {
    __syncthreads();
    #pragma unroll
    for (int mi = 0; mi < MT; mi++)
      #pragma unroll
      for (int ni = 0; ni < NT; ni++) {
        int n = nbase + ni * 16 + l15;            // 0..63
        float b = (n >= 32) ? bias[n - 32] : 0.f;
        #pragma unroll
        for (int r = 0; r < 4; r++)
          sA[(mbase + mi * 16 + lq * 4 + r) * 72 + n] =
              f2bf(acc[mi][ni][r] + b);
      }
    __syncthreads();
    int row = tid >> 2, c0 = (tid & 3) * 16;
    int gn = nb + row;
    if (gn < NN) {
      uint4 v0 = *(uint4*)&sA[row * 72 + c0];
      uint4 v1 = *(uint4*)&sA[row * 72 + c0 + 8];
      if (c0 < 32) {
        *(uint4*)&yl[(size_t)gn * 32 + c0] = v0;
        *(uint4*)&yl[(size_t)gn * 32 + c0 + 8] = v1;
      } else {
        *(uint4*)&yr[(size_t)gn * 32 + (c0 - 32)] = v0;
        *(uint4*)&yr[(size_t)gn * 32 + (c0 - 32) + 8] = v1;
      }
    }
  }
}

template <int NC>
__global__ __launch_bounds__(512) void k_mgemm(
    const unsigned short* __restrict__ A, const unsigned short* __restrict__ Bp,
    const float* __restrict__ bias,
    unsigned short* __restrict__ yl, unsigned short* __restrict__ yr, int gb) {
  __shared__ unsigned short sA[128 * 136];
  mgemmN_body<NC>(sA, (blockIdx.x + gb) * 128, A, Bp, bias, yl, yr);
}

// ---------------- 128-dim aggregation: one wave, one node ----------------
#define ACC8(u) do { \
  A01 += up2((u).x); A23 += up2((u).y); \
  A45 += up2((u).z); A67 += up2((u).w); } while (0)

__device__ __forceinline__ void agg128_wave(
    int wid, int lane, const unsigned short* __restrict__ yl,
    const unsigned short* __restrict__ yr, const int* __restrict__ off,
    const int* __restrict__ csr, const float* __restrict__ invd,
    unsigned short* __restrict__ out) {
  int beg = off[wid], end = off[wid + 1];
  int deg = end - beg;
  int q   = lane >> 4;
  int l16 = lane & 15;
  const uint4* ylp = (const uint4*)yl;

  float sc = invd[wid];
  uint4 rv = ((const uint4*)yr)[wid * 16 + l16];

  f32x2 A01 = (f32x2){0.f, 0.f}, A23 = (f32x2){0.f, 0.f};
  f32x2 A45 = (f32x2){0.f, 0.f}, A67 = (f32x2){0.f, 0.f};

  for (int w0 = 0; w0 < deg; w0 += 64) {
    int ei = w0 + lane;
    int sv = (ei < deg) ? csr[beg + ei] : 0;
    int wcnt = deg - w0; if (wcnt > 64) wcnt = 64;
    int full = wcnt >> 2;
    int p = 0;
    for (; p + 4 <= full; p += 4) {
      int b = p * 4 + q;
      int s0 = __shfl(sv, b,      64);
      int s1 = __shfl(sv, b + 4,  64);
      int s2 = __shfl(sv, b + 8,  64);
      int s3 = __shfl(sv, b + 12, 64);
      uint4 u0 = ylp[s0 * 16 + l16];
      uint4 u1 = ylp[s1 * 16 + l16];
      uint4 u2 = ylp[s2 * 16 + l16];
      uint4 u3 = ylp[s3 * 16 + l16];
      ACC8(u0); ACC8(u1); ACC8(u2); ACC8(u3);
    }
    for (; p < full; p++) {
      int s0 = __shfl(sv, p * 4 + q, 64);
      uint4 u0 = ylp[s0 * 16 + l16];
      ACC8(u0);
    }
    int rem = wcnt & 3;
    if (rem && q < rem) {
      int s0 = __shfl(sv, full * 4 + q, 64);
      uint4 u0 = ylp[s0 * 16 + l16];
      ACC8(u0);
    }
  }

  float a0 = A01.x, a1 = A01.y, a2 = A23.x, a3 = A23.y;
  float a4 = A45.x, a5 = A45.y, a6 = A67.x, a7 = A67.y;

  a0 += __shfl_xor(a0, 16, 64); a0 += __shfl_xor(a0, 32, 64);
  a1 += __shfl_xor(a1, 16, 64); a1 += __shfl_xor(a1, 32, 64);
  a2 += __shfl_xor(a2, 16, 64); a2 += __shfl_xor(a2, 32, 64);
  a3 += __shfl_xor(a3, 16, 64); a3 += __shfl_xor(a3, 32, 64);
  a4 += __shfl_xor(a4, 16, 64); a4 += __shfl_xor(a4, 32, 64);
  a5 += __shfl_xor(a5, 16, 64); a5 += __shfl_xor(a5, 32, 64);
  a6 += __shfl_xor(a6, 16, 64); a6 += __shfl_xor(a6, 32, 64);
  a7 += __shfl_xor(a7, 16, 64); a7 += __shfl_xor(a7, 32, 64);

  float v0 = fmaxf(a0 * sc + bflo(rv.x), 0.f);
  float v1 = fmaxf(a1 * sc + bfhi(rv.x), 0.f);
  float v2 = fmaxf(a2 * sc + bflo(rv.y), 0.f);
  float v3 = fmaxf(a3 * sc + bfhi(rv.y), 0.f);
  float v4 = fmaxf(a4 * sc + bflo(rv.z), 0.f);
  float v5 = fmaxf(a5 * sc + bfhi(rv.z), 0.f);
  float v6 = fmaxf(a6 * sc + bflo(rv.w), 0.f);
  float v7 = fmaxf(a7 * sc + bfhi(rv.w), 0.f);
  if (q == 0) {
    unsigned int p0 = (unsigned int)f2bf(v0) | ((unsigned int)f2bf(v1) << 16);
    unsigned int p1 = (unsigned int)f2bf(v2) | ((unsigned int)f2bf(v3) << 16);
    unsigned int p2 = (unsigned int)f2bf(v4) | ((unsigned int)f2bf(v5) << 16);
    unsigned int p3 = (unsigned int)f2bf(v6) | ((unsigned int)f2bf(v7) << 16);
    ((uint4*)out)[wid * 16 + l16] = make_uint4(p0, p1, p2, p3);
  }
}

__global__ __launch_bounds__(256) void k_agg128(
    const unsigned short* __restrict__ yl, const unsigned short* __restrict__ yr,
    const int* __restrict__ off, const int* __restrict__ csr,
    const float* __restrict__ invd, unsigned short* __restrict__ out,
    int base, int lim) {
  int wid = base + ((blockIdx.x * 256 + threadIdx.x) >> 6);
  if (wid >= lim) return;
  agg128_wave(wid, threadIdx.x & 63, yl, yr, off, csr, invd, out);
}

// ---------------- fused: agg128(half2) + mgemm<NC>(half1) ----------------
// bid%17==0 -> gemm block bid/17 (reads hb[0,HNN)); else agg node
// HNN + (bid - bid/17 - 1)*8 + wave (writes hb[HNN,NN)). Disjoint rows.
template <int NC>
__global__ __launch_bounds__(512, 4) void k_agggemm(
    const unsigned short* __restrict__ ylin, const unsigned short* __restrict__ yrin,
    const int* __restrict__ off, const int* __restrict__ csr,
    const float* __restrict__ invd, unsigned short* __restrict__ hb,
    const unsigned short* __restrict__ Bp, const float* __restrict__ bias,
    unsigned short* __restrict__ outl, unsigned short* __restrict__ outr) {
  __shared__ unsigned short sA[128 * 136];
  int bid = blockIdx.x;
  int g = bid / 17;
  if (bid - g * 17 == 0) {
    mgemmN_body<NC>(sA, g * 128, hb, Bp, bias, outl, outr);
  } else {
    int idx = bid - g - 1;
    int wid = HNN + idx * 8 + (threadIdx.x >> 6);
    if (wid < NN)
      agg128_wave(wid, threadIdx.x & 63, ylin, yrin, off, csr, invd, hb);
  }
}

// ---------------- 32-dim aggregation + log_softmax ----------------
#define ACC4(u) do { \
  A01 += up2((u).x); A23 += up2((u).y); } while (0)

__global__ __launch_bounds__(256) void k_agg32_lsm(
    const unsigned short* __restrict__ yl, const unsigned short* __restrict__ yr,
    const int* __restrict__ off, const int* __restrict__ csr,
    const float* __restrict__ invd, float* __restrict__ out) {
  int wid  = (blockIdx.x * 256 + threadIdx.x) >> 6;
  int lane = threadIdx.x & 63;
  if (wid >= NN) return;
  int beg = off[wid], end = off[wid + 1];
  int deg = end - beg;
  int q  = lane >> 3;
  int l8 = lane & 7;
  const uint2* ylp = (const uint2*)yl;

  float sc = invd[wid];
  uint2 rv = ((const uint2*)yr)[wid * 8 + l8];

  f32x2 A01 = (f32x2){0.f, 0.f}, A23 = (f32x2){0.f, 0.f};

  for (int w0 = 0; w0 < deg; w0 += 64) {
    int ei = w0 + lane;
    int sv = (ei < deg) ? csr[beg + ei] : 0;
    int wcnt = deg - w0; if (wcnt > 64) wcnt = 64;
    int full = wcnt >> 3;
    int p = 0;
    for (; p + 2 <= full; p += 2) {
      int b = p * 8 + q;
      int s0 = __shfl(sv, b,     64);
      int s1 = __shfl(sv, b + 8, 64);
      uint2 u0 = ylp[s0 * 8 + l8];
      uint2 u1 = ylp[s1 * 8 + l8];
      ACC4(u0); ACC4(u1);
    }
    for (; p < full; p++) {
      int s0 = __shfl(sv, p * 8 + q, 64);
      uint2 u0 = ylp[s0 * 8 + l8];
      ACC4(u0);
    }
    int rem = wcnt & 7;
    if (rem && q < rem) {
      int s0 = __shfl(sv, full * 8 + q, 64);
      uint2 u0 = ylp[s0 * 8 + l8];
      ACC4(u0);
    }
  }

  float a0 = A01.x, a1 = A01.y, a2 = A23.x, a3 = A23.y;

  a0 += __shfl_xor(a0, 8, 64); a0 += __shfl_xor(a0, 16, 64); a0 += __shfl_xor(a0, 32, 64);
  a1 += __shfl_xor(a1, 8, 64); a1 += __shfl_xor(a1, 16, 64); a1 += __shfl_xor(a1, 32, 64);
  a2 += __shfl_xor(a2, 8, 64); a2 += __shfl_xor(a2, 16, 64); a2 += __shfl_xor(a2, 32, 64);
  a3 += __shfl_xor(a3, 8, 64); a3 += __shfl_xor(a3, 16, 64); a3 += __shfl_xor(a3, 32, 64);

  float v0 = a0 * sc + bflo(rv.x), v1 = a1 * sc + bfhi(rv.x);
  float v2 = a2 * sc + bflo(rv.y), v3 = a3 * sc + bfhi(rv.y);

  float m = fmaxf(fmaxf(v0, v1), fmaxf(v2, v3));
  m = fmaxf(m, __shfl_xor(m, 1, 64));
  m = fmaxf(m, __shfl_xor(m, 2, 64));
  m = fmaxf(m, __shfl_xor(m, 4, 64));
  float e0 = expf(v0 - m), e1 = expf(v1 - m);
  float e2 = expf(v2 - m), e3 = expf(v3 - m);
  float s = (e0 + e1) + (e2 + e3);
  s += __shfl_xor(s, 1, 64);
  s += __shfl_xor(s, 2, 64);
  s += __shfl_xor(s, 4, 64);
  float ls = logf(s);
  if (q == 0) {
    float4 o = make_float4(v0 - m - ls, v1 - m - ls, v2 - m - ls, v3 - m - ls);
    ((float4*)out)[wid * 8 + l8] = o;
  }
}

// ---------------- launch ----------------

extern "C" void kernel_launch(void* const* d_in, const int* in_sizes, int n_in,
                              void* d_out, int out_size, void* d_ws, size_t ws_size,
                              hipStream_t stream) {
  (void)in_sizes; (void)n_in; (void)out_size;
  const float* x   = (const float*)d_in[0];
  const int*   ei  = (const int*)d_in[1];
  const float* Wl0 = (const float*)d_in[2];
  const float* bl0 = (const float*)d_in[3];
  const float* Wr0 = (const float*)d_in[4];
  const float* Wl1 = (const float*)d_in[5];
  const float* bl1 = (const float*)d_in[6];
  const float* Wr1 = (const float*)d_in[7];
  const float* Wl2 = (const float*)d_in[8];
  const float* bl2 = (const float*)d_in[9];
  const float* Wr2 = (const float*)d_in[10];
  const int* srcI = ei;
  const int* dstI = ei + NE;

  char* w = (char*)d_ws;
  int*   cboff  = (int*)(w + (32 << 10));                       // 392 ints
  unsigned short* B0 = (unsigned short*)(w + (64 << 10));       // 64 KB
  unsigned short* B1 = (unsigned short*)(w + (160 << 10));      // 64 KB
  unsigned short* B2 = (unsigned short*)(w + (256 << 10));      // 16 KB
  int*   part   = (int*)(w + (288 << 10));                      // 200 KB
  int*   ccur   = (int*)(w + (496 << 10));                      // 25 KB
  int*   csroff = (int*)(w + (1024 << 10));                     // 400 KB
  float* invd   = (float*)(w + (1536 << 10));                   // 400 KB
  unsigned int* ebuf = (unsigned int*)(w + (size_t)(2) * 1024 * 1024);   // 6.4 MB
  int*   csrsrc = (int*)(w + (size_t)(9) * 1024 * 1024);                 // 6.4 MB
  unsigned short* yl0 = (unsigned short*)(w + (size_t)(16) * 1024 * 1024); // 25.6 MB
  unsigned short* yr0 = (unsigned short*)(w + (size_t)(48) * 1024 * 1024); // 25.6 MB
  unsigned short* hb  = (unsigned short*)(w + (size_t)(80) * 1024 * 1024); // 25.6 MB
  unsigned short* yl1 = (unsigned short*)(w + (size_t)(112) * 1024 * 1024); // 25.6 MB (pipelined only)
  // layer-2 outputs (6.4 MB each) reuse the dead yl0 region
  unsigned short* yl2 = (unsigned short*)(w + (size_t)(16) * 1024 * 1024);
  unsigned short* yr2 = (unsigned short*)(w + (size_t)(26) * 1024 * 1024);

  // 1: histogram + weight prep
  k_prep<<<HBK + WPB, 512, 0, stream>>>(dstI, part, Wl0, Wr0, Wl1, Wr1, Wl2, Wr2,
                                        B0, B1, B2);
  // 2: scan
  k_cscan<<<1, 512, 0, stream>>>(part, cboff, ccur, csroff);
  // 3: edge scatter + layer-0 GEMM (1:2 interleave, EB=4096 — proven R7)
  k_scatgemm<<<NSB + NGB, 512, 0, stream>>>(srcI, dstI, cboff, ccur, ebuf,
                                            x, B0, bl0, yl0, yr0);
  // 4: CSR refine
  k_crefine<<<NCB, 512, 0, stream>>>(ebuf, cboff, csroff, invd, csrsrc);

  if (ws_size >= ((size_t)144 << 20)) {
    // ---- pipelined layer boundaries (needs yl1 buffer) ----
    // L0 -> L1
    k_agg128<<<HNN / 4, 256, 0, stream>>>(yl0, yr0, csroff, csrsrc, invd, hb,
                                          0, HNN);
    k_agggemm<256><<<6635, 512, 0, stream>>>(yl0, yr0, csroff, csrsrc, invd,
                                             hb, B1, bl1, yl1, yr0);
    k_mgemm<256><<<HGB, 512, 0, stream>>>(hb, B1, bl1, yl1, yr0, HGB);
    // L1 -> L2
    k_agg128<<<HNN / 4, 256, 0, stream>>>(yl1, yr0, csroff, csrsrc, invd, hb,
                                          0, HNN);
    k_agggemm<64><<<6635, 512, 0, stream>>>(yl1, yr0, csroff, csrsrc, invd,
                                            hb, B2, bl2, yl2, yr2);
    k_mgemm<64><<<HGB, 512, 0, stream>>>(hb, B2, bl2, yl2, yr2, HGB);
    // final
    k_agg32_lsm<<<(NN * 64) / 256, 256, 0, stream>>>(yl2, yr2, csroff, csrsrc,
                                                     invd, (float*)d_out);
  } else {
    // ---- serial fallback (proven R7 flow, 3 buffers) ----
    k_agg128<<<(NN * 64) / 256, 256, 0, stream>>>(yl0, yr0, csroff, csrsrc,
                                                  invd, hb, 0, NN);
    k_mgemm<256><<<NGB, 512, 0, stream>>>(hb, B1, bl1, yl0, yr0, 0);
    k_agg128<<<(NN * 64) / 256, 256, 0, stream>>>(yl0, yr0, csroff, csrsrc,
                                                  invd, hb, 0, NN);
    k_mgemm<64><<<NGB, 512, 0, stream>>>(hb, B2, bl2, yl2, yr2, 0);
    k_agg32_lsm<<<(NN * 64) / 256, 256, 0, stream>>>(yl2, yr2, csroff, csrsrc,
                                                     invd, (float*)d_out);
  }
}

// Round 10
// 388.831 us; speedup vs baseline: 1.0659x; 1.0597x over previous
//
#include <hip/hip_runtime.h>
#include <hip/hip_bf16.h>
#include <math.h>

#define NN 100000
#define NE 1600000

#define NCB 391             // coarse buckets of 256 nodes
#define EB  4096            // edges per scatter block
#define SCT 512             // scatter block threads
#define EPT 8               // edges per thread = EB/SCT
#define HBK 128             // histogram blocks
#define NSB 391             // scatter blocks = ceil(NE/EB)
#define WPB 144             // wprep blocks (73728/512)
#define NGB 782             // gemm blocks = ceil(NN/128)

typedef __attribute__((ext_vector_type(8))) short short8;
typedef __attribute__((ext_vector_type(4))) float f32x4;
typedef __attribute__((ext_vector_type(2))) float f32x2;

// ---------- bf16 helpers ----------
__device__ __forceinline__ unsigned short f2bf(float f) {
  union { float f; unsigned int i; } v; v.f = f;
  unsigned int i = v.i;
  unsigned int r = (i + 0x7FFFu + ((i >> 16) & 1u)) >> 16;   // RNE
  return (unsigned short)r;
}
__device__ __forceinline__ float bflo(unsigned int u) {
  union { unsigned int i; float f; } v; v.i = u << 16; return v.f;
}
__device__ __forceinline__ float bfhi(unsigned int u) {
  union { unsigned int i; float f; } v; v.i = u & 0xFFFF0000u; return v.f;
}
// unpack bf16x2 -> packed f32x2 (compiler emits v_pk_add_f32 for f32x2 adds)
__device__ __forceinline__ f32x2 up2(unsigned int u) {
  union { unsigned int i; float f; } lo, hi;
  lo.i = u << 16; hi.i = u & 0xFFFF0000u;
  return (f32x2){lo.f, hi.f};
}

// ---------------- fused prep: bucket histogram (blocks 0..HBK-1) + weight
// prep (blocks HBK..HBK+WPB-1). wprep is CSR-independent; hide it here. ----
__global__ __launch_bounds__(512) void k_prep(
    const int* __restrict__ dst, int* __restrict__ part,
    const float* __restrict__ Wl0, const float* __restrict__ Wr0,
    const float* __restrict__ Wl1, const float* __restrict__ Wr1,
    const float* __restrict__ Wl2, const float* __restrict__ Wr2,
    unsigned short* __restrict__ B0, unsigned short* __restrict__ B1,
    unsigned short* __restrict__ B2) {
  if (blockIdx.x < HBK) {
    __shared__ int h[NCB];
    for (int i = threadIdx.x; i < NCB; i += 512) h[i] = 0;
    __syncthreads();
    int stride = HBK * 512;
    for (int e = blockIdx.x * 512 + threadIdx.x; e < NE; e += stride) {
      int d = dst[e];
      d = d < 0 ? 0 : (d >= NN ? NN - 1 : d);
      atomicAdd(&h[d >> 8], 1);
    }
    __syncthreads();
    for (int i = threadIdx.x; i < NCB; i += 512) part[blockIdx.x * NCB + i] = h[i];
  } else {
    int idx = (blockIdx.x - HBK) * 512 + threadIdx.x;   // [0, 73728)
    if (idx < 32768) {
      int n = idx >> 7, k = idx & 127;
      float v = (n < 128) ? Wl0[k * 128 + n] : Wr0[k * 128 + (n - 128)];
      B0[idx] = f2bf(v);
    } else if (idx < 65536) {
      int j = idx - 32768;
      int n = j >> 7, k = j & 127;
      float v = (n < 128) ? Wl1[k * 128 + n] : Wr1[k * 128 + (n - 128)];
      B1[j] = f2bf(v);
    } else if (idx < 73728) {
      int j = idx - 65536;
      int n = j >> 7, k = j & 127;
      float v = (n < 32) ? Wl2[k * 32 + n] : Wr2[k * 32 + (n - 32)];
      B2[j] = f2bf(v);
    }
  }
}

// ---------------- scan of coarse counts; zeroes ccur (64B-strided) --------
__global__ __launch_bounds__(512) void k_cscan(const int* __restrict__ part,
                                               int* __restrict__ cboff,
                                               int* __restrict__ ccur,
                                               int* __restrict__ csroff) {
  __shared__ int sd[512];
  int t = threadIdx.x;
  int v = 0;
  if (t < NCB) {
    int s0 = 0, s1 = 0, s2 = 0, s3 = 0;
    #pragma unroll 4
    for (int k = 0; k < HBK; k += 4) {
      s0 += part[(k + 0) * NCB + t];
      s1 += part[(k + 1) * NCB + t];
      s2 += part[(k + 2) * NCB + t];
      s3 += part[(k + 3) * NCB + t];
    }
    v = (s0 + s1) + (s2 + s3);
    ccur[t * 16] = 0;            // one counter per 64B line
  }
  sd[t] = v;
  __syncthreads();
  for (int st = 1; st < 512; st <<= 1) {
    int x = (t >= st) ? sd[t - st] : 0;
    __syncthreads();
    sd[t] += x;
    __syncthreads();
  }
  if (t < NCB) cboff[t] = sd[t] - v;
  if (t == NCB - 1) { cboff[NCB] = sd[t]; csroff[NN] = sd[t]; }
}

// ---------------- fused scatter + layer-0 MFMA GEMM ----------------
// 1173 = 3*NSB blocks; bid%3==0 -> scatter (1 of 3), else gemm (2 of 3).
// Proven R7 config: EB=4096, 1:2 interleave.

__device__ __forceinline__ void cscatter_body(
    char* smem, int bid,
    const int* __restrict__ src, const int* __restrict__ dst,
    const int* __restrict__ cboff, int* __restrict__ ccur,
    unsigned int* __restrict__ ebuf) {
  int* lh = (int*)smem;                                  // NCB ints
  int t = threadIdx.x;
  int base = bid * EB;
  for (int i = t; i < NCB; i += SCT) lh[i] = 0;
  __syncthreads();
  unsigned int rk[EPT], pv[EPT];
  #pragma unroll
  for (int i = 0; i < EPT; i++) {
    int e = base + i * SCT + t;
    rk[i] = 0xFFFFFFFFu;
    pv[i] = 0;
    if (e < NE) {
      int d = dst[e];
      d = d < 0 ? 0 : (d >= NN ? NN - 1 : d);
      int s = src[e];
      s = s < 0 ? 0 : (s >= NN ? NN - 1 : s);
      int cb = d >> 8;
      int r = atomicAdd(&lh[cb], 1);
      rk[i] = (((unsigned int)cb) << 13) | (unsigned int)r;
      pv[i] = (((unsigned int)(d & 255)) << 17) | (unsigned int)s;
    }
  }
  __syncthreads();
  for (int i = t; i < NCB; i += SCT) {
    int c = lh[i];
    int g = c ? atomicAdd(&ccur[i * 16], c) : 0;
    lh[i] = cboff[i] + g;
  }
  __syncthreads();
  #pragma unroll
  for (int i = 0; i < EPT; i++) {
    unsigned int r = rk[i];
    if (r != 0xFFFFFFFFu) {
      ebuf[lh[r >> 13] + (r & 0x1FFF)] = pv[i];
    }
  }
}

// LDS-staged coalesced epilogue (NC=256): acc -> sA (bf16, MFMA layout) ->
// linear uint4 flush. Two passes: yl (cols 0..127, waves wn<2), then yr
// (cols 128..255, waves wn>=2, +bias). 128x128 bf16 @ stride 136 = 34 KB.
__device__ __forceinline__ void epilogue256(
    unsigned short* sA, int tid, int nb, int wn, int mbase, int nbase,
    int l15, int lq, f32x4 acc[4][4], const float* __restrict__ bias,
    unsigned short* __restrict__ yl, unsigned short* __restrict__ yr) {
  __syncthreads();
  if (wn < 2) {
    #pragma unroll
    for (int mi = 0; mi < 4; mi++)
      #pragma unroll
      for (int ni = 0; ni < 4; ni++) {
        int n = nbase + ni * 16 + l15;
        #pragma unroll
        for (int r = 0; r < 4; r++)
          sA[(mbase + mi * 16 + lq * 4 + r) * 136 + n] = f2bf(acc[mi][ni][r]);
      }
  }
  __syncthreads();
  {
    int row = tid >> 2, c0 = (tid & 3) * 32;
    int gn = nb + row;
    if (gn < NN) {
      #pragma unroll
      for (int k = 0; k < 4; k++) {
        uint4 v = *(uint4*)&sA[row * 136 + c0 + k * 8];
        *(uint4*)&yl[(size_t)gn * 128 + c0 + k * 8] = v;
      }
    }
  }
  __syncthreads();
  if (wn >= 2) {
    #pragma unroll
    for (int mi = 0; mi < 4; mi++)
      #pragma unroll
      for (int ni = 0; ni < 4; ni++) {
        int n2 = nbase - 128 + ni * 16 + l15;
        float b = bias[n2];
        #pragma unroll
        for (int r = 0; r < 4; r++)
          sA[(mbase + mi * 16 + lq * 4 + r) * 136 + n2] =
              f2bf(acc[mi][ni][r] + b);
      }
  }
  __syncthreads();
  {
    int row = tid >> 2, c0 = (tid & 3) * 32;
    int gn = nb + row;
    if (gn < NN) {
      #pragma unroll
      for (int k = 0; k < 4; k++) {
        uint4 v = *(uint4*)&sA[row * 136 + c0 + k * 8];
        *(uint4*)&yr[(size_t)gn * 128 + c0 + k * 8] = v;
      }
    }
  }
}

__device__ __forceinline__ void mgemm0_body(
    char* smem, int bid, const float* __restrict__ A,
    const unsigned short* __restrict__ Bp, const float* __restrict__ bias,
    unsigned short* __restrict__ yl, unsigned short* __restrict__ yr) {
  unsigned short* sA = (unsigned short*)smem;   // 128*136*2 = 34.8 KB
  int tid = threadIdx.x;
  int nb  = bid * 128;

  #pragma unroll
  for (int i = 0; i < 8; i++) {
    int j = i * 512 + tid;
    int m = j >> 5;
    int k4 = (j & 31) * 4;
    int gn = nb + m;
    float4 v = make_float4(0.f, 0.f, 0.f, 0.f);
    if (gn < NN) v = *(const float4*)&A[gn * 128 + k4];
    unsigned int p0 = (unsigned int)f2bf(v.x) | ((unsigned int)f2bf(v.y) << 16);
    unsigned int p1 = (unsigned int)f2bf(v.z) | ((unsigned int)f2bf(v.w) << 16);
    *(uint2*)&sA[m * 136 + k4] = make_uint2(p0, p1);
  }
  __syncthreads();

  int wave = tid >> 6, lane = tid & 63;
  int l15 = lane & 15, lq = lane >> 4;
  int wm = wave & 1, wn = wave >> 1;
  int mbase = wm * 64;
  int nbase = wn * 64;

  f32x4 acc[4][4];
  #pragma unroll
  for (int mi = 0; mi < 4; mi++)
    #pragma unroll
    for (int ni = 0; ni < 4; ni++) acc[mi][ni] = (f32x4){0.f, 0.f, 0.f, 0.f};

  #pragma unroll
  for (int kc = 0; kc < 4; kc++) {
    int k0 = kc * 32 + lq * 8;
    short8 af[4], bfr[4];
    #pragma unroll
    for (int ni = 0; ni < 4; ni++)
      bfr[ni] = *(const short8*)&Bp[(nbase + ni * 16 + l15) * 128 + k0];
    #pragma unroll
    for (int mi = 0; mi < 4; mi++)
      af[mi] = *(const short8*)&sA[(mbase + mi * 16 + l15) * 136 + k0];
    #pragma unroll
    for (int mi = 0; mi < 4; mi++)
      #pragma unroll
      for (int ni = 0; ni < 4; ni++)
        acc[mi][ni] = __builtin_amdgcn_mfma_f32_16x16x32_bf16(
            af[mi], bfr[ni], acc[mi][ni], 0, 0, 0);
  }

  epilogue256(sA, tid, nb, wn, mbase, nbase, l15, lq, acc, bias, yl, yr);
}

__global__ __launch_bounds__(512, 4) void k_scatgemm(
    const int* __restrict__ src, const int* __restrict__ dst,
    const int* __restrict__ cboff, int* __restrict__ ccur,
    unsigned int* __restrict__ ebuf,
    const float* __restrict__ x, const unsigned short* __restrict__ B0,
    const float* __restrict__ bias,
    unsigned short* __restrict__ yl, unsigned short* __restrict__ yr) {
  __shared__ char smem[128 * 136 * 2];   // 34.8 KB union (gemm sA / scatter lh)
  int bid = blockIdx.x;
  int third = bid / 3;
  if (bid - third * 3 == 0) {
    cscatter_body(smem, third, src, dst, cboff, ccur, ebuf);
  } else {
    mgemm0_body(smem, bid - third - 1, x, B0, bias, yl, yr);
  }
}

// ---------------- per-coarse-bucket refine -> exact CSR (512 thr) ----------
__global__ __launch_bounds__(512) void k_crefine(
    const unsigned int* __restrict__ ebuf, const int* __restrict__ cboff,
    int* __restrict__ csroff, float* __restrict__ invd,
    int* __restrict__ csrsrc) {
  __shared__ int lh[256], pos[256], cur[256];
  int b = blockIdx.x, t = threadIdx.x;
  if (t < 256) { lh[t] = 0; cur[t] = 0; }
  __syncthreads();
  int beg = cboff[b], end = cboff[b + 1];
  for (int i = beg + t; i < end; i += 512) atomicAdd(&lh[ebuf[i] >> 17], 1);
  __syncthreads();
  int v = 0;
  if (t < 256) { v = lh[t]; pos[t] = v; }
  __syncthreads();
  for (int st = 1; st < 256; st <<= 1) {
    int x = (t < 256 && t >= st) ? pos[t - st] : 0;
    __syncthreads();
    if (t < 256) pos[t] += x;
    __syncthreads();
  }
  if (t < 256) {
    int nid = b * 256 + t;
    int mybase = cboff[b] + pos[t] - v;
    if (nid < NN) {
      csroff[nid] = mybase;
      invd[nid] = 1.0f / (float)(v < 1 ? 1 : v);
    }
    pos[t] = mybase;
  }
  __syncthreads();
  for (int i = beg + t; i < end; i += 512) {
    unsigned int u = ebuf[i];
    int local = u >> 17;
    int r = atomicAdd(&cur[local], 1);
    csrsrc[pos[local] + r] = (int)(u & 0x1FFFFu);
  }
}

// ---------------- standalone MFMA GEMM (layers 1,2; bf16 A) ----------------
template <int NC>
__global__ __launch_bounds__(512) void k_mgemm(
    const unsigned short* __restrict__ A, const unsigned short* __restrict__ Bp,
    const float* __restrict__ bias,
    unsigned short* __restrict__ yl, unsigned short* __restrict__ yr) {
  __shared__ unsigned short sA[128 * 136];
  int tid = threadIdx.x;
  int nb  = blockIdx.x * 128;

  #pragma unroll
  for (int i = 0; i < 4; i++) {
    int j = i * 512 + tid;
    int m = j >> 4;
    int k8 = (j & 15) * 8;
    int gn = nb + m;
    uint4 v = make_uint4(0, 0, 0, 0);
    if (gn < NN) v = *(const uint4*)&A[gn * 128 + k8];
    *(uint4*)&sA[m * 136 + k8] = v;
  }
  __syncthreads();

  int wave = tid >> 6, lane = tid & 63;
  int l15 = lane & 15, lq = lane >> 4;
  constexpr int MT = (NC == 256) ? 4 : 2;
  constexpr int NT = (NC == 256) ? 4 : 2;
  int wm, wn;
  if (NC == 256) { wm = wave & 1; wn = wave >> 1; }
  else           { wm = wave >> 1; wn = wave & 1; }
  int mbase = wm * (MT * 16);
  int nbase = wn * (NT * 16);

  f32x4 acc[MT][NT];
  #pragma unroll
  for (int mi = 0; mi < MT; mi++)
    #pragma unroll
    for (int ni = 0; ni < NT; ni++) acc[mi][ni] = (f32x4){0.f, 0.f, 0.f, 0.f};

  #pragma unroll
  for (int kc = 0; kc < 4; kc++) {
    int k0 = kc * 32 + lq * 8;
    short8 af[MT], bfr[NT];
    #pragma unroll
    for (int ni = 0; ni < NT; ni++)
      bfr[ni] = *(const short8*)&Bp[(nbase + ni * 16 + l15) * 128 + k0];
    #pragma unroll
    for (int mi = 0; mi < MT; mi++)
      af[mi] = *(const short8*)&sA[(mbase + mi * 16 + l15) * 136 + k0];
    #pragma unroll
    for (int mi = 0; mi < MT; mi++)
      #pragma unroll
      for (int ni = 0; ni < NT; ni++)
        acc[mi][ni] = __builtin_amdgcn_mfma_f32_16x16x32_bf16(
            af[mi], bfr[ni], acc[mi][ni], 0, 0, 0);
  }

  if (NC == 256) {
    f32x4 (*a)[4] = (f32x4(*)[4])acc;
    epilogue256(sA, tid, nb, wn, mbase, nbase, l15, lq, a, bias, yl, yr);
  } else {
    // single-pass staged epilogue: 128 rows x 64 cols bf16 @ stride 72 (18 KB)
    __syncthreads();
    #pragma unroll
    for (int mi = 0; mi < MT; mi++)
      #pragma unroll
      for (int ni = 0; ni < NT; ni++) {
        int n = nbase + ni * 16 + l15;            // 0..63
        float b = (n >= 32) ? bias[n - 32] : 0.f;
        #pragma unroll
        for (int r = 0; r < 4; r++)
          sA[(mbase + mi * 16 + lq * 4 + r) * 72 + n] =
              f2bf(acc[mi][ni][r] + b);
      }
    __syncthreads();
    int row = tid >> 2, c0 = (tid & 3) * 16;      // 16 cols (32 B) per thread
    int gn = nb + row;
    if (gn < NN) {
      uint4 v0 = *(uint4*)&sA[row * 72 + c0];
      uint4 v1 = *(uint4*)&sA[row * 72 + c0 + 8];
      if (c0 < 32) {
        *(uint4*)&yl[(size_t)gn * 32 + c0] = v0;
        *(uint4*)&yl[(size_t)gn * 32 + c0 + 8] = v1;
      } else {
        *(uint4*)&yr[(size_t)gn * 32 + (c0 - 32)] = v0;
        *(uint4*)&yr[(size_t)gn * 32 + (c0 - 32) + 8] = v1;
      }
    }
  }
}

// ---------------- pull aggregation, 128-dim (packed-f32 accumulate) --------
#define ACC8(u) do { \
  A01 += up2((u).x); A23 += up2((u).y); \
  A45 += up2((u).z); A67 += up2((u).w); } while (0)

__global__ __launch_bounds__(256) void k_agg128(
    const unsigned short* __restrict__ yl, const unsigned short* __restrict__ yr,
    const int* __restrict__ off, const int* __restrict__ csr,
    const float* __restrict__ invd, unsigned short* __restrict__ out, int relu) {
  int wid  = (blockIdx.x * 256 + threadIdx.x) >> 6;
  int lane = threadIdx.x & 63;
  if (wid >= NN) return;
  int beg = off[wid], end = off[wid + 1];
  int deg = end - beg;
  int q   = lane >> 4;    // edge slot within a 4-edge group
  int l16 = lane & 15;    // dim group: dims [l16*8, l16*8+8)
  const uint4* ylp = (const uint4*)yl;   // row = 16 uint4

  float sc = invd[wid];
  uint4 rv = ((const uint4*)yr)[wid * 16 + l16];

  f32x2 A01 = (f32x2){0.f, 0.f}, A23 = (f32x2){0.f, 0.f};
  f32x2 A45 = (f32x2){0.f, 0.f}, A67 = (f32x2){0.f, 0.f};

  for (int w0 = 0; w0 < deg; w0 += 64) {
    int ei = w0 + lane;
    int sv = (ei < deg) ? csr[beg + ei] : 0;
    int wcnt = deg - w0; if (wcnt > 64) wcnt = 64;
    int full = wcnt >> 2;
    int p = 0;
    for (; p + 4 <= full; p += 4) {          // 16 edges in flight
      int b = p * 4 + q;
      int s0 = __shfl(sv, b,      64);
      int s1 = __shfl(sv, b + 4,  64);
      int s2 = __shfl(sv, b + 8,  64);
      int s3 = __shfl(sv, b + 12, 64);
      uint4 u0 = ylp[s0 * 16 + l16];
      uint4 u1 = ylp[s1 * 16 + l16];
      uint4 u2 = ylp[s2 * 16 + l16];
      uint4 u3 = ylp[s3 * 16 + l16];
      ACC8(u0); ACC8(u1); ACC8(u2); ACC8(u3);
    }
    for (; p < full; p++) {
      int s0 = __shfl(sv, p * 4 + q, 64);
      uint4 u0 = ylp[s0 * 16 + l16];
      ACC8(u0);
    }
    int rem = wcnt & 3;
    if (rem && q < rem) {
      int s0 = __shfl(sv, full * 4 + q, 64);
      uint4 u0 = ylp[s0 * 16 + l16];
      ACC8(u0);
    }
  }

  float a0 = A01.x, a1 = A01.y, a2 = A23.x, a3 = A23.y;
  float a4 = A45.x, a5 = A45.y, a6 = A67.x, a7 = A67.y;

  // combine across the 4 quarter-groups
  a0 += __shfl_xor(a0, 16, 64); a0 += __shfl_xor(a0, 32, 64);
  a1 += __shfl_xor(a1, 16, 64); a1 += __shfl_xor(a1, 32, 64);
  a2 += __shfl_xor(a2, 16, 64); a2 += __shfl_xor(a2, 32, 64);
  a3 += __shfl_xor(a3, 16, 64); a3 += __shfl_xor(a3, 32, 64);
  a4 += __shfl_xor(a4, 16, 64); a4 += __shfl_xor(a4, 32, 64);
  a5 += __shfl_xor(a5, 16, 64); a5 += __shfl_xor(a5, 32, 64);
  a6 += __shfl_xor(a6, 16, 64); a6 += __shfl_xor(a6, 32, 64);
  a7 += __shfl_xor(a7, 16, 64); a7 += __shfl_xor(a7, 32, 64);

  float v0 = a0 * sc + bflo(rv.x), v1 = a1 * sc + bfhi(rv.x);
  float v2 = a2 * sc + bflo(rv.y), v3 = a3 * sc + bfhi(rv.y);
  float v4 = a4 * sc + bflo(rv.z), v5 = a5 * sc + bfhi(rv.z);
  float v6 = a6 * sc + bflo(rv.w), v7 = a7 * sc + bfhi(rv.w);
  if (relu) {
    v0 = fmaxf(v0, 0.f); v1 = fmaxf(v1, 0.f);
    v2 = fmaxf(v2, 0.f); v3 = fmaxf(v3, 0.f);
    v4 = fmaxf(v4, 0.f); v5 = fmaxf(v5, 0.f);
    v6 = fmaxf(v6, 0.f); v7 = fmaxf(v7, 0.f);
  }
  if (q == 0) {
    unsigned int p0 = (unsigned int)f2bf(v0) | ((unsigned int)f2bf(v1) << 16);
    unsigned int p1 = (unsigned int)f2bf(v2) | ((unsigned int)f2bf(v3) << 16);
    unsigned int p2 = (unsigned int)f2bf(v4) | ((unsigned int)f2bf(v5) << 16);
    unsigned int p3 = (unsigned int)f2bf(v6) | ((unsigned int)f2bf(v7) << 16);
    ((uint4*)out)[wid * 16 + l16] = make_uint4(p0, p1, p2, p3);
  }
}

// ---------------- 32-dim aggregation + log_softmax ----------------
#define ACC4(u) do { \
  A01 += up2((u).x); A23 += up2((u).y); } while (0)

__global__ __launch_bounds__(256) void k_agg32_lsm(
    const unsigned short* __restrict__ yl, const unsigned short* __restrict__ yr,
    const int* __restrict__ off, const int* __restrict__ csr,
    const float* __restrict__ invd, float* __restrict__ out) {
  int wid  = (blockIdx.x * 256 + threadIdx.x) >> 6;
  int lane = threadIdx.x & 63;
  if (wid >= NN) return;
  int beg = off[wid], end = off[wid + 1];
  int deg = end - beg;
  int q  = lane >> 3;     // edge slot 0..7
  int l8 = lane & 7;      // dims [l8*4, l8*4+4)
  const uint2* ylp = (const uint2*)yl;   // row = 8 uint2

  float sc = invd[wid];
  uint2 rv = ((const uint2*)yr)[wid * 8 + l8];

  f32x2 A01 = (f32x2){0.f, 0.f}, A23 = (f32x2){0.f, 0.f};

  for (int w0 = 0; w0 < deg; w0 += 64) {
    int ei = w0 + lane;
    int sv = (ei < deg) ? csr[beg + ei] : 0;
    int wcnt = deg - w0; if (wcnt > 64) wcnt = 64;
    int full = wcnt >> 3;
    int p = 0;
    for (; p + 2 <= full; p += 2) {         // 16 edges in flight
      int b = p * 8 + q;
      int s0 = __shfl(sv, b,     64);
      int s1 = __shfl(sv, b + 8, 64);
      uint2 u0 = ylp[s0 * 8 + l8];
      uint2 u1 = ylp[s1 * 8 + l8];
      ACC4(u0); ACC4(u1);
    }
    for (; p < full; p++) {
      int s0 = __shfl(sv, p * 8 + q, 64);
      uint2 u0 = ylp[s0 * 8 + l8];
      ACC4(u0);
    }
    int rem = wcnt & 7;
    if (rem && q < rem) {
      int s0 = __shfl(sv, full * 8 + q, 64);
      uint2 u0 = ylp[s0 * 8 + l8];
      ACC4(u0);
    }
  }

  float a0 = A01.x, a1 = A01.y, a2 = A23.x, a3 = A23.y;

  // combine across the 8 edge slots
  a0 += __shfl_xor(a0, 8, 64); a0 += __shfl_xor(a0, 16, 64); a0 += __shfl_xor(a0, 32, 64);
  a1 += __shfl_xor(a1, 8, 64); a1 += __shfl_xor(a1, 16, 64); a1 += __shfl_xor(a1, 32, 64);
  a2 += __shfl_xor(a2, 8, 64); a2 += __shfl_xor(a2, 16, 64); a2 += __shfl_xor(a2, 32, 64);
  a3 += __shfl_xor(a3, 8, 64); a3 += __shfl_xor(a3, 16, 64); a3 += __shfl_xor(a3, 32, 64);

  float v0 = a0 * sc + bflo(rv.x), v1 = a1 * sc + bfhi(rv.x);
  float v2 = a2 * sc + bflo(rv.y), v3 = a3 * sc + bfhi(rv.y);

  float m = fmaxf(fmaxf(v0, v1), fmaxf(v2, v3));
  m = fmaxf(m, __shfl_xor(m, 1, 64));
  m = fmaxf(m, __shfl_xor(m, 2, 64));
  m = fmaxf(m, __shfl_xor(m, 4, 64));
  float e0 = expf(v0 - m), e1 = expf(v1 - m);
  float e2 = expf(v2 - m), e3 = expf(v3 - m);
  float s = (e0 + e1) + (e2 + e3);
  s += __shfl_xor(s, 1, 64);
  s += __shfl_xor(s, 2, 64);
  s += __shfl_xor(s, 4, 64);
  float ls = logf(s);
  if (q == 0) {
    float4 o = make_float4(v0 - m - ls, v1 - m - ls, v2 - m - ls, v3 - m - ls);
    ((float4*)out)[wid * 8 + l8] = o;
  }
}

// ---------------- launch ----------------

extern "C" void kernel_launch(void* const* d_in, const int* in_sizes, int n_in,
                              void* d_out, int out_size, void* d_ws, size_t ws_size,
                              hipStream_t stream) {
  (void)in_sizes; (void)n_in; (void)out_size; (void)ws_size;
  const float* x   = (const float*)d_in[0];
  const int*   ei  = (const int*)d_in[1];
  const float* Wl0 = (const float*)d_in[2];
  const float* bl0 = (const float*)d_in[3];
  const float* Wr0 = (const float*)d_in[4];
  const float* Wl1 = (const float*)d_in[5];
  const float* bl1 = (const float*)d_in[6];
  const float* Wr1 = (const float*)d_in[7];
  const float* Wl2 = (const float*)d_in[8];
  const float* bl2 = (const float*)d_in[9];
  const float* Wr2 = (const float*)d_in[10];
  const int* srcI = ei;
  const int* dstI = ei + NE;

  char* w = (char*)d_ws;
  int*   cboff  = (int*)(w + (32 << 10));                       // 392 ints
  unsigned short* B0 = (unsigned short*)(w + (64 << 10));       // 64 KB
  unsigned short* B1 = (unsigned short*)(w + (160 << 10));      // 64 KB
  unsigned short* B2 = (unsigned short*)(w + (256 << 10));      // 16 KB
  int*   part   = (int*)(w + (288 << 10));                      // 128*391 = 200 KB
  int*   ccur   = (int*)(w + (496 << 10));                      // 391*64B = 25 KB
  int*   csroff = (int*)(w + (1024 << 10));                     // 400 KB
  float* invd   = (float*)(w + (1536 << 10));                   // 400 KB
  unsigned int* ebuf = (unsigned int*)(w + (size_t)(2) * 1024 * 1024);   // 6.4 MB
  int*   csrsrc = (int*)(w + (size_t)(9) * 1024 * 1024);                 // 6.4 MB
  unsigned short* ylb = (unsigned short*)(w + (size_t)(16) * 1024 * 1024); // 25.6 MB
  unsigned short* yrb = (unsigned short*)(w + (size_t)(48) * 1024 * 1024); // 25.6 MB
  unsigned short* hb  = (unsigned short*)(w + (size_t)(80) * 1024 * 1024); // 25.6 MB

  dim3 gg(NGB);   // 782

  // 1: histogram + weight prep (independent work, one dispatch)
  k_prep<<<HBK + WPB, 512, 0, stream>>>(dstI, part, Wl0, Wr0, Wl1, Wr1, Wl2, Wr2,
                                        B0, B1, B2);
  // 2: scan
  k_cscan<<<1, 512, 0, stream>>>(part, cboff, ccur, csroff);
  // 3: edge scatter + layer-0 GEMM (1:2 interleave, EB=4096 — proven R7)
  k_scatgemm<<<NSB + NGB, 512, 0, stream>>>(srcI, dstI, cboff, ccur, ebuf,
                                            x, B0, bl0, ylb, yrb);
  // 4: CSR refine
  k_crefine<<<NCB, 512, 0, stream>>>(ebuf, cboff, csroff, invd, csrsrc);
  // 5: layer-0 aggregation
  k_agg128<<<(NN * 64) / 256, 256, 0, stream>>>(ylb, yrb, csroff, csrsrc, invd, hb, 1);
  // 6: layer-1 GEMM
  k_mgemm<256><<<gg, 512, 0, stream>>>(hb, B1, bl1, ylb, yrb);
  // 7: layer-1 aggregation
  k_agg128<<<(NN * 64) / 256, 256, 0, stream>>>(ylb, yrb, csroff, csrsrc, invd, hb, 1);
  // 8: layer-2 GEMM (transform-first, 32-dim)
  k_mgemm<64><<<gg, 512, 0, stream>>>(hb, B2, bl2, ylb, yrb);
  // 9: layer-2 aggregation + log_softmax
  k_agg32_lsm<<<(NN * 64) / 256, 256, 0, stream>>>(ylb, yrb, csroff, csrsrc, invd,
                                                   (float*)d_out);
}